// Round 3
// baseline (269.867 us; speedup 1.0000x reference)
//
#include <hip/hip_runtime.h>
#include <cstdint>
#include <cstddef>

// Problem constants
//   x[1024,256] f32, W1[1024,256] f32, b1[1024], W2[32896,1024] f32, b2[32896]
//   h = softplus(x@W1^T + b1)          [1024,1024]  (bf16 in ws)
//   elements = h@W2^T + b2             first TRI=32640 cols used
//   out[b,i,j] = elements[b, i(i-1)/2+j] for i>j; out[b,j,i] = -that; diag 0
#define TRI 32640
#define NPAD 32768          // N padded to 128 x 256-tiles (rows exist in W2)

using u32   = unsigned int;
using u16   = unsigned short;
using f32x4 = __attribute__((ext_vector_type(4))) float;
using u32x4 = __attribute__((ext_vector_type(4))) u32;
using bf16x8 = __attribute__((ext_vector_type(8))) short;

__device__ __forceinline__ void gload_lds16(const void* g, void* l) {
  // async global->LDS, 16B/lane; LDS dest = wave-uniform base + lane*16
  __builtin_amdgcn_global_load_lds(
      (const __attribute__((address_space(1))) void*)g,
      (__attribute__((address_space(3))) void*)l, 16, 0, 0);
}

__device__ __forceinline__ u32 pack2bf(float a, float b) {
  u32 ua = __builtin_bit_cast(u32, a);
  u32 ub = __builtin_bit_cast(u32, b);
  return (ub & 0xffff0000u) | (ua >> 16);
}

__device__ __forceinline__ u16 f2bf_rn(float f) {  // round-to-nearest-even
  u32 u = __builtin_bit_cast(u32, f);
  u += 0x7fffu + ((u >> 16) & 1u);
  return (u16)(u >> 16);
}

// ---------------------------------------------------------------------------
// K0 (fused): blocks 0-63   : h = softplus(x @ W1^T + b1), bf16 (m97-style)
//             blocks 64-1087: convert W2[0:NPAD,:] f32 -> bf16(rn) into ws
// ---------------------------------------------------------------------------
__global__ __launch_bounds__(256)
void k0_fused(const float* __restrict__ x, const float* __restrict__ W1,
              const float* __restrict__ b1, u16* __restrict__ h,
              const float* __restrict__ W2, u16* __restrict__ W2b)
{
  __shared__ float ldsA[128*32];
  __shared__ float ldsB[128*32];

  if (blockIdx.x >= 64) {
    const int g0 = (blockIdx.x - 64)*256 + threadIdx.x;
    const f32x4* src = (const f32x4*)W2;
    const int n4 = NPAD*1024/4;           // 8,388,608 (exact, 32 iters)
    for (int v = g0; v < n4; v += 1024*256) {
      f32x4 f = src[v];
      uint2 p;
      p.x = (u32)f2bf_rn(f.x) | ((u32)f2bf_rn(f.y) << 16);
      p.y = (u32)f2bf_rn(f.z) | ((u32)f2bf_rn(f.w) << 16);
      *(uint2*)(W2b + (size_t)v*4) = p;
    }
    return;
  }

  const int tid = threadIdx.x, lane = tid & 63, wave = tid >> 6;
  const int wm = wave >> 1, wn = wave & 1;
  const int brow = (blockIdx.x & 7) * 128, bcol = (blockIdx.x >> 3) * 128;

  const int s_row = wave*8 + (lane >> 3);
  const int s_col = (lane & 7) * 4;
  const float* gA = x  + (brow + s_row)*256 + s_col;
  const float* gB = W1 + (bcol + s_row)*256 + s_col;
  float* lA = &ldsA[wave*256];
  float* lB = &ldsB[wave*256];

  const int fr = lane & 15, fk = (lane >> 4) * 8;
  const float* rdA = &ldsA[(wm*64 + fr)*32 + fk];
  const float* rdB = &ldsB[(wn*64 + fr)*32 + fk];

  f32x4 acc[4][4] = {};
  for (int kt = 0; kt < 8; ++kt) {
    __syncthreads();
#pragma unroll
    for (int q = 0; q < 4; ++q) {
      gload_lds16(gA + q*32*256 + kt*32, lA + q*1024);
      gload_lds16(gB + q*32*256 + kt*32, lB + q*1024);
    }
    __syncthreads();
    bf16x8 af[4], bfv[4];
#pragma unroll
    for (int m = 0; m < 4; ++m) {
      f32x4 lo = *(const f32x4*)(rdA + m*512);
      f32x4 hi = *(const f32x4*)(rdA + m*512 + 4);
      u32x4 p = { pack2bf(lo.x,lo.y), pack2bf(lo.z,lo.w),
                  pack2bf(hi.x,hi.y), pack2bf(hi.z,hi.w) };
      af[m] = __builtin_bit_cast(bf16x8, p);
    }
#pragma unroll
    for (int n = 0; n < 4; ++n) {
      f32x4 lo = *(const f32x4*)(rdB + n*512);
      f32x4 hi = *(const f32x4*)(rdB + n*512 + 4);
      u32x4 p = { pack2bf(lo.x,lo.y), pack2bf(lo.z,lo.w),
                  pack2bf(hi.x,hi.y), pack2bf(hi.z,hi.w) };
      bfv[n] = __builtin_bit_cast(bf16x8, p);
    }
#pragma unroll
    for (int m = 0; m < 4; ++m)
#pragma unroll
      for (int n = 0; n < 4; ++n)
        acc[m][n] = __builtin_amdgcn_mfma_f32_16x16x32_bf16(af[m], bfv[n], acc[m][n], 0,0,0);
  }
#pragma unroll
  for (int n = 0; n < 4; ++n) {
    const int col = bcol + wn*64 + n*16 + fr;
    const float bias = b1[col];
#pragma unroll
    for (int m = 0; m < 4; ++m) {
      const int row0 = brow + wm*64 + m*16 + (lane >> 4)*4;
#pragma unroll
      for (int r = 0; r < 4; ++r) {
        float z = acc[m][n][r] + bias;
        float sp = fmaxf(z, 0.f) + log1pf(expf(-fabsf(z)));
        h[(row0 + r)*1024 + col] = f2bf_rn(sp);
      }
    }
  }
}

// ---------------------------------------------------------------------------
// K2: elements = h @ W2b^T (+b2), forward-half scatter.
// 256x256 tile, BK=32, 8 waves (2M x 4N), double-buffered LDS, counted
// vmcnt prefetch (T3/T4), LDS unit-swizzle (T2), setprio (T5).
// M=1024, N=32768 (padded), K=1024. Grid 4x128 = 512 blocks, 512 threads.
//
// LDS swizzle (64B rows, 4x16B units/row): unit ^= (row>>1)&3.
//   16 lanes reading rows r..r+15 at fixed unit hit 8 distinct 16B slots
//   (2-way = free); full-wave b128 access touches each byte exactly once.
//   global_load_lds writes linearly -> SOURCE is inverse-permuted (rule #21).
// ---------------------------------------------------------------------------
__global__ __launch_bounds__(512, 2)
void k2_gemm_pipelined(const u16* __restrict__ h, const u16* __restrict__ W2b,
                       const float* __restrict__ b2, float* __restrict__ out)
{
  __shared__ u16 ldsA[2][256*32];   // 2 x 16 KB
  __shared__ u16 ldsB[2][256*32];   // 2 x 16 KB

  const int tid = threadIdx.x, lane = tid & 63, wv = tid >> 6;   // wv 0..7
  const int wr = wv >> 2, wc = wv & 3;                           // 2M x 4N

  // XCD-bijective swizzle (512 % 8 == 0): 4 m-tiles sharing a B-panel are
  // consecutive logical blocks -> same XCD chunk.
  const int L = (blockIdx.x & 7) * 64 + (blockIdx.x >> 3);
  const int brow = (L & 3) * 256;          // batch tile
  const int t0   = (L >> 2) * 256;         // t tile

  // staging: per wave 2 issues per operand; issue q covers 16 rows.
  const int sr  = lane >> 2;               // row within issue (0..15)
  const int su0 = lane & 3;                // linear unit this lane fills

  // fragment read constants: rows == fr (mod 16) for every fragment, so the
  // swizzle XOR depends only on the lane.
  const int fr = lane & 15, u0 = lane >> 4;            // u0 = k-unit 0..3
  const int xu = ((u0 ^ ((fr >> 1) & 3)) << 3);        // swizzled elem offset

  f32x4 acc[8][4] = {};

#define STAGE_AB(kt, buf)                                                     \
  {                                                                           \
    _Pragma("unroll")                                                         \
    for (int q = 0; q < 2; ++q) {                                             \
      const int r  = (wv*2 + q)*16 + sr;                                      \
      const int su = su0 ^ ((r >> 1) & 3);                                    \
      gload_lds16(h   + (size_t)(brow + r)*1024 + (kt)*32 + su*8,             \
                  &ldsA[buf][(wv*2 + q)*512]);                                \
      gload_lds16(W2b + (size_t)(t0  + r)*1024 + (kt)*32 + su*8,              \
                  &ldsB[buf][(wv*2 + q)*512]);                                \
    }                                                                         \
  }

  // prologue: K-tiles 0 and 1 in flight; wait for tile 0 (keep tile 1's 4).
  STAGE_AB(0, 0)
  STAGE_AB(1, 1)
  asm volatile("s_waitcnt vmcnt(4)" ::: "memory");
  __builtin_amdgcn_s_barrier();
  asm volatile("" ::: "memory");

  int cur = 0;
  for (int kt = 0; kt < 32; ++kt) {
    const u16* A = ldsA[cur];
    const u16* B = ldsB[cur];
    bf16x8 af[8], bfv[4];
#pragma unroll
    for (int m = 0; m < 8; ++m)
      af[m] = *(const bf16x8*)(A + (wr*128 + m*16 + fr)*32 + xu);
#pragma unroll
    for (int n = 0; n < 4; ++n)
      bfv[n] = *(const bf16x8*)(B + (wc*64 + n*16 + fr)*32 + xu);

    __builtin_amdgcn_s_setprio(1);
#pragma unroll
    for (int m = 0; m < 8; ++m)
#pragma unroll
      for (int n = 0; n < 4; ++n)
        acc[m][n] = __builtin_amdgcn_mfma_f32_16x16x32_bf16(af[m], bfv[n], acc[m][n], 0,0,0);
    __builtin_amdgcn_s_setprio(0);

    if (kt == 31) break;
    // all waves' reads of buf[cur] are consumed (MFMA reg-dep forced lgkmcnt)
    asm volatile("" ::: "memory");
    __builtin_amdgcn_s_barrier();
    asm volatile("" ::: "memory");
    if (kt + 2 < 32) {
      STAGE_AB(kt + 2, cur)                 // reuse buf just freed
      asm volatile("s_waitcnt vmcnt(4)" ::: "memory");   // kt+1 landed
    } else {
      asm volatile("s_waitcnt vmcnt(0)" ::: "memory");   // drain tail
    }
    __builtin_amdgcn_s_barrier();           // buf[cur^1] ready for all waves
    asm volatile("" ::: "memory");
    cur ^= 1;
  }
#undef STAGE_AB

  // epilogue: t -> (i,j) strict-lower scatter, forward half only.
#pragma unroll
  for (int n = 0; n < 4; ++n) {
    const int t = t0 + wc*64 + n*16 + fr;
    if (t >= TRI) continue;
    const float bias = b2[t];
    int i = (int)((1.0f + sqrtf((float)(8*t + 1))) * 0.5f);
    while (i*(i+1)/2 <= t) ++i;
    while (i*(i-1)/2 > t) --i;
    const int j = t - i*(i-1)/2;
    const int ijbase = i*256 + j;
#pragma unroll
    for (int m = 0; m < 8; ++m) {
      const int row0 = brow + wr*128 + m*16 + (lane >> 4)*4;
#pragma unroll
      for (int r = 0; r < 4; ++r)
        out[(size_t)(row0 + r)*65536 + ijbase] = acc[m][n][r] + bias;
    }
  }
}

// ---------------------------------------------------------------------------
// Fallback path (ws too small): round-1 kernels, proven correct.
// ---------------------------------------------------------------------------
__global__ __launch_bounds__(256)
void k1_gemm_softplus(const float* __restrict__ x, const float* __restrict__ W1,
                      const float* __restrict__ b1, u16* __restrict__ h)
{
  __shared__ float ldsA[128*32];
  __shared__ float ldsB[128*32];
  const int tid = threadIdx.x, lane = tid & 63, wave = tid >> 6;
  const int wm = wave >> 1, wn = wave & 1;
  const int brow = (blockIdx.x & 7) * 128, bcol = (blockIdx.x >> 3) * 128;
  const int s_row = wave*8 + (lane >> 3);
  const int s_col = (lane & 7) * 4;
  const float* gA = x  + (brow + s_row)*256 + s_col;
  const float* gB = W1 + (bcol + s_row)*256 + s_col;
  float* lA = &ldsA[wave*256];
  float* lB = &ldsB[wave*256];
  const int fr = lane & 15, fk = (lane >> 4) * 8;
  const float* rdA = &ldsA[(wm*64 + fr)*32 + fk];
  const float* rdB = &ldsB[(wn*64 + fr)*32 + fk];
  f32x4 acc[4][4] = {};
  for (int kt = 0; kt < 8; ++kt) {
    __syncthreads();
#pragma unroll
    for (int q = 0; q < 4; ++q) {
      gload_lds16(gA + q*32*256 + kt*32, lA + q*1024);
      gload_lds16(gB + q*32*256 + kt*32, lB + q*1024);
    }
    __syncthreads();
    bf16x8 af[4], bfv[4];
#pragma unroll
    for (int m = 0; m < 4; ++m) {
      f32x4 lo = *(const f32x4*)(rdA + m*512);
      f32x4 hi = *(const f32x4*)(rdA + m*512 + 4);
      u32x4 p = { pack2bf(lo.x,lo.y), pack2bf(lo.z,lo.w),
                  pack2bf(hi.x,hi.y), pack2bf(hi.z,hi.w) };
      af[m] = __builtin_bit_cast(bf16x8, p);
    }
#pragma unroll
    for (int n = 0; n < 4; ++n) {
      f32x4 lo = *(const f32x4*)(rdB + n*512);
      f32x4 hi = *(const f32x4*)(rdB + n*512 + 4);
      u32x4 p = { pack2bf(lo.x,lo.y), pack2bf(lo.z,lo.w),
                  pack2bf(hi.x,hi.y), pack2bf(hi.z,hi.w) };
      bfv[n] = __builtin_bit_cast(bf16x8, p);
    }
#pragma unroll
    for (int m = 0; m < 4; ++m)
#pragma unroll
      for (int n = 0; n < 4; ++n)
        acc[m][n] = __builtin_amdgcn_mfma_f32_16x16x32_bf16(af[m], bfv[n], acc[m][n], 0,0,0);
  }
#pragma unroll
  for (int n = 0; n < 4; ++n) {
    const int col = bcol + wn*64 + n*16 + fr;
    const float bias = b1[col];
#pragma unroll
    for (int m = 0; m < 4; ++m) {
      const int row0 = brow + wm*64 + m*16 + (lane >> 4)*4;
#pragma unroll
      for (int r = 0; r < 4; ++r) {
        float z = acc[m][n][r] + bias;
        float sp = fmaxf(z, 0.f) + log1pf(expf(-fabsf(z)));
        h[(row0 + r)*1024 + col] = f2bf_rn(sp);
      }
    }
  }
}

__global__ __launch_bounds__(256)
void k2_gemm_scatter(const u16* __restrict__ h, const float* __restrict__ W2,
                     const float* __restrict__ b2, float* __restrict__ out)
{
  __shared__ u16   ldsA[128*32];
  __shared__ float ldsB[128*32];
  const int tid = threadIdx.x, lane = tid & 63, wave = tid >> 6;
  const int wm = wave >> 1, wn = wave & 1;
  const int bid = blockIdx.x;
  const int L  = (bid & 7) * 255 + (bid >> 3);
  const int t0 = (L >> 3) * 128;
  const int brow = (L & 7) * 128;
  const int a_row = wave*16 + (lane >> 2);
  const int a_col = (lane & 3) * 8;
  const u16* gA = h + (brow + a_row)*1024 + a_col;
  u16* lA = &ldsA[wave*512];
  const int b_row = wave*8 + (lane >> 3);
  const int b_col = (lane & 7) * 4;
  const float* gB = W2 + (size_t)(t0 + b_row)*1024 + b_col;
  float* lB = &ldsB[wave*256];
  const int fr = lane & 15, fk = (lane >> 4) * 8;
  const u16*   rdA = &ldsA[(wm*64 + fr)*32 + fk];
  const float* rdB = &ldsB[(wn*64 + fr)*32 + fk];
  f32x4 acc[4][4] = {};
  for (int kt = 0; kt < 32; ++kt) {
    __syncthreads();
#pragma unroll
    for (int q = 0; q < 2; ++q)
      gload_lds16(gA + q*64*1024 + kt*32, lA + q*2048);
#pragma unroll
    for (int q = 0; q < 4; ++q)
      gload_lds16(gB + q*32*1024 + kt*32, lB + q*1024);
    __syncthreads();
    bf16x8 af[4];
#pragma unroll
    for (int m = 0; m < 4; ++m)
      af[m] = *(const bf16x8*)(rdA + m*512);
#pragma unroll
    for (int n = 0; n < 4; ++n) {
      f32x4 lo = *(const f32x4*)(rdB + n*512);
      f32x4 hi = *(const f32x4*)(rdB + n*512 + 4);
      u32x4 p = { pack2bf(lo.x,lo.y), pack2bf(lo.z,lo.w),
                  pack2bf(hi.x,hi.y), pack2bf(hi.z,hi.w) };
      bf16x8 bfr = __builtin_bit_cast(bf16x8, p);
#pragma unroll
      for (int m = 0; m < 4; ++m)
        acc[m][n] = __builtin_amdgcn_mfma_f32_16x16x32_bf16(af[m], bfr, acc[m][n], 0,0,0);
    }
  }
#pragma unroll
  for (int n = 0; n < 4; ++n) {
    const int t = t0 + wn*64 + n*16 + fr;
    const float bias = b2[t];
    int i = (int)((1.0f + sqrtf((float)(8*t + 1))) * 0.5f);
    while (i*(i+1)/2 <= t) ++i;
    while (i*(i-1)/2 > t) --i;
    const int j = t - i*(i-1)/2;
    const int ijbase = i*256 + j;
#pragma unroll
    for (int m = 0; m < 4; ++m) {
      const int row0 = brow + wm*64 + m*16 + (lane >> 4)*4;
#pragma unroll
      for (int r = 0; r < 4; ++r)
        out[(size_t)(row0 + r)*65536 + ijbase] = acc[m][n][r] + bias;
    }
  }
}

// ---------------------------------------------------------------------------
// K3: antisymmetrize. Read lower 64x64 tiles, write -tile^T to upper.
// ---------------------------------------------------------------------------
__global__ __launch_bounds__(256)
void k3_mirror(float* __restrict__ out)
{
  __shared__ float tile[64][65];
  const int b = blockIdx.y;
  const int k = blockIdx.x;
  int ib, jb;
  if (k < 4) { ib = k; jb = k; }
  else {
    const int pi[6] = {1,2,2,3,3,3};
    const int pj[6] = {0,0,1,0,1,2};
    ib = pi[k-4]; jb = pj[k-4];
  }
  const int i0 = ib*64, j0 = jb*64;
  float* A = out + (size_t)b*65536;
  const int tid = threadIdx.x;
  const int r = tid >> 2, c0 = (tid & 3) * 16;
#pragma unroll
  for (int q = 0; q < 4; ++q) {
    const float4 v = *(const float4*)(A + (i0 + r)*256 + j0 + c0 + q*4);
    tile[r][c0+q*4+0] = v.x;
    tile[r][c0+q*4+1] = v.y;
    tile[r][c0+q*4+2] = v.z;
    tile[r][c0+q*4+3] = v.w;
  }
  __syncthreads();
  if (ib != jb) {
#pragma unroll
    for (int q = 0; q < 4; ++q) {
      const int c = c0 + q*4;
      float4 v;
      v.x = -tile[c+0][r]; v.y = -tile[c+1][r];
      v.z = -tile[c+2][r]; v.w = -tile[c+3][r];
      *(float4*)(A + (j0 + r)*256 + i0 + c) = v;
    }
  } else {
#pragma unroll
    for (int q = 0; q < 4; ++q) {
      const int cb = c0 + q*4;
      float4 v;
#pragma unroll
      for (int e = 0; e < 4; ++e) {
        const int c = cb + e;
        float val = (c < r) ? tile[r][c] : ((c == r) ? 0.f : -tile[c][r]);
        ((float*)&v)[e] = val;
      }
      *(float4*)(A + (i0 + r)*256 + j0 + cb) = v;
    }
  }
}

// ---------------------------------------------------------------------------
extern "C" void kernel_launch(void* const* d_in, const int* in_sizes, int n_in,
                              void* d_out, int out_size, void* d_ws, size_t ws_size,
                              hipStream_t stream) {
  const float* x  = (const float*)d_in[0];
  const float* W1 = (const float*)d_in[1];
  const float* b1 = (const float*)d_in[2];
  const float* W2 = (const float*)d_in[3];
  const float* b2 = (const float*)d_in[4];
  float* out = (float*)d_out;
  u16* h = (u16*)d_ws;                               // 2 MB

  const size_t need = 2u*1024*1024 + (size_t)NPAD*1024*2;   // h + W2 bf16 (padded)
  if (ws_size >= need) {
    u16* W2b = (u16*)((char*)d_ws + 2u*1024*1024);
    k0_fused         <<<dim3(64 + 1024), dim3(256), 0, stream>>>(x, W1, b1, h, W2, W2b);
    k2_gemm_pipelined<<<dim3(512),       dim3(512), 0, stream>>>(h, W2b, b2, out);
  } else {
    k1_gemm_softplus <<<dim3(64),        dim3(256), 0, stream>>>(x, W1, b1, h);
    k2_gemm_scatter  <<<dim3(2040),      dim3(256), 0, stream>>>(h, W2, b2, out);
  }
  k3_mirror          <<<dim3(10, 1024),  dim3(256), 0, stream>>>(out);
}

// Round 4
// 246.786 us; speedup vs baseline: 1.0935x; 1.0935x over previous
//
#include <hip/hip_runtime.h>
#include <cstdint>
#include <cstddef>

// Problem constants
//   x[1024,256] f32, W1[1024,256] f32, b1[1024], W2[32896,1024] f32, b2[32896]
//   h = softplus(x@W1^T + b1)          [1024,1024]  (bf16 in ws)
//   elements = h@W2^T + b2             first TRI=32640 cols used
//   out[b,i,j] = elements[b, i(i-1)/2+j] for i>j; out[b,j,i] = -that; diag 0
#define TRI 32640
#define NPAD 32768          // N padded to 128 x 256-tiles (rows exist in W2)

using u32   = unsigned int;
using u16   = unsigned short;
using f32x4 = __attribute__((ext_vector_type(4))) float;
using u32x4 = __attribute__((ext_vector_type(4))) u32;
using bf16x8 = __attribute__((ext_vector_type(8))) short;

__device__ __forceinline__ void gload_lds16(const void* g, void* l) {
  // async global->LDS, 16B/lane; LDS dest = wave-uniform base + lane*16
  __builtin_amdgcn_global_load_lds(
      (const __attribute__((address_space(1))) void*)g,
      (__attribute__((address_space(3))) void*)l, 16, 0, 0);
}

__device__ __forceinline__ u32 pack2bf(float a, float b) {
  u32 ua = __builtin_bit_cast(u32, a);
  u32 ub = __builtin_bit_cast(u32, b);
  return (ub & 0xffff0000u) | (ua >> 16);
}

__device__ __forceinline__ u16 f2bf_rn(float f) {  // round-to-nearest-even
  u32 u = __builtin_bit_cast(u32, f);
  u += 0x7fffu + ((u >> 16) & 1u);
  return (u16)(u >> 16);
}

#define MEMFENCE asm volatile("" ::: "memory")

// ---------------------------------------------------------------------------
// K0 (fused): blocks 0-63   : h = softplus(x @ W1^T + b1), bf16 (m97-style)
//             blocks 64-1087: convert W2[0:NPAD,:] f32 -> bf16(rn) into ws
// ---------------------------------------------------------------------------
__global__ __launch_bounds__(256)
void k0_fused(const float* __restrict__ x, const float* __restrict__ W1,
              const float* __restrict__ b1, u16* __restrict__ h,
              const float* __restrict__ W2, u16* __restrict__ W2b)
{
  __shared__ float ldsA[128*32];
  __shared__ float ldsB[128*32];

  if (blockIdx.x >= 64) {
    const int g0 = (blockIdx.x - 64)*256 + threadIdx.x;
    const f32x4* src = (const f32x4*)W2;
    const int n4 = NPAD*1024/4;           // 8,388,608 (exact, 32 iters)
    for (int v = g0; v < n4; v += 1024*256) {
      f32x4 f = src[v];
      uint2 p;
      p.x = (u32)f2bf_rn(f.x) | ((u32)f2bf_rn(f.y) << 16);
      p.y = (u32)f2bf_rn(f.z) | ((u32)f2bf_rn(f.w) << 16);
      *(uint2*)(W2b + (size_t)v*4) = p;
    }
    return;
  }

  const int tid = threadIdx.x, lane = tid & 63, wave = tid >> 6;
  const int wm = wave >> 1, wn = wave & 1;
  const int brow = (blockIdx.x & 7) * 128, bcol = (blockIdx.x >> 3) * 128;

  const int s_row = wave*8 + (lane >> 3);
  const int s_col = (lane & 7) * 4;
  const float* gA = x  + (brow + s_row)*256 + s_col;
  const float* gB = W1 + (bcol + s_row)*256 + s_col;
  float* lA = &ldsA[wave*256];
  float* lB = &ldsB[wave*256];

  const int fr = lane & 15, fk = (lane >> 4) * 8;
  const float* rdA = &ldsA[(wm*64 + fr)*32 + fk];
  const float* rdB = &ldsB[(wn*64 + fr)*32 + fk];

  f32x4 acc[4][4] = {};
  for (int kt = 0; kt < 8; ++kt) {
    __syncthreads();
#pragma unroll
    for (int q = 0; q < 4; ++q) {
      gload_lds16(gA + q*32*256 + kt*32, lA + q*1024);
      gload_lds16(gB + q*32*256 + kt*32, lB + q*1024);
    }
    __syncthreads();
    bf16x8 af[4], bfv[4];
#pragma unroll
    for (int m = 0; m < 4; ++m) {
      f32x4 lo = *(const f32x4*)(rdA + m*512);
      f32x4 hi = *(const f32x4*)(rdA + m*512 + 4);
      u32x4 p = { pack2bf(lo.x,lo.y), pack2bf(lo.z,lo.w),
                  pack2bf(hi.x,hi.y), pack2bf(hi.z,hi.w) };
      af[m] = __builtin_bit_cast(bf16x8, p);
    }
#pragma unroll
    for (int n = 0; n < 4; ++n) {
      f32x4 lo = *(const f32x4*)(rdB + n*512);
      f32x4 hi = *(const f32x4*)(rdB + n*512 + 4);
      u32x4 p = { pack2bf(lo.x,lo.y), pack2bf(lo.z,lo.w),
                  pack2bf(hi.x,hi.y), pack2bf(hi.z,hi.w) };
      bfv[n] = __builtin_bit_cast(bf16x8, p);
    }
#pragma unroll
    for (int m = 0; m < 4; ++m)
#pragma unroll
      for (int n = 0; n < 4; ++n)
        acc[m][n] = __builtin_amdgcn_mfma_f32_16x16x32_bf16(af[m], bfv[n], acc[m][n], 0,0,0);
  }
#pragma unroll
  for (int n = 0; n < 4; ++n) {
    const int col = bcol + wn*64 + n*16 + fr;
    const float bias = b1[col];
#pragma unroll
    for (int m = 0; m < 4; ++m) {
      const int row0 = brow + wm*64 + m*16 + (lane >> 4)*4;
#pragma unroll
      for (int r = 0; r < 4; ++r) {
        float z = acc[m][n][r] + bias;
        float sp = fmaxf(z, 0.f) + log1pf(expf(-fabsf(z)));
        h[(row0 + r)*1024 + col] = f2bf_rn(sp);
      }
    }
  }
}

// ---------------------------------------------------------------------------
// K2: elements = h @ W2b^T (+b2), forward-half scatter.
// 8-phase-style fine interleave (T3+T4), BK=32, 2 phases/K-tile, 32 K-tiles.
// 256x256 tile, 8 waves (2M x 4N), per-wave 128x64 out. LDS 64 KB static:
// 2 parities x {A 16K, B 16K}. One half-tile staged per phase (2 gload/thr),
// ONE counted vmcnt(2) per K-tile (j1 end) - never drained in-loop.
//
// Stage schedule (slot-lifetime derived):
//   j0(t): stage B(t+1) -> parity (t+1)&1   (B(t-1) slot freed at t-1 j1)
//   j1(t): stage A(t+2) -> parity t&1       (A(t) reads done at j0 lgkmcnt)
// Deadlines: B(t+1) & A(t+1) must land by t's j1-end -> vmcnt(2) leaves only
// A(t+2)'s 2 loads outstanding. Tail: clamp staged k-index to 31; restages
// write identical bytes (benign) keeping vmcnt counts uniform.
//
// LDS unit-swizzle (round-3-proven, 0 conflicts): 64B rows, 4x16B units,
// unit ^= (row>>1)&3, applied both-sides (inverse-permuted global source for
// linear gload_lds dest + swizzled ds_read address).
// ---------------------------------------------------------------------------
__global__ __launch_bounds__(512)
void k2_gemm_8phase(const u16* __restrict__ h, const u16* __restrict__ W2b,
                    const float* __restrict__ b2, float* __restrict__ out)
{
  __shared__ u16 lds[32768];      // 64 KB: [parity 32KB][A 16KB | B 16KB]

  const int tid = threadIdx.x, lane = tid & 63, wv = tid >> 6;   // wv 0..7
  const int wr = wv >> 2, wc = wv & 3;                           // 2M x 4N

  // XCD-bijective swizzle (512 % 8 == 0): 4 m-tiles sharing a B-panel are
  // consecutive logical blocks -> same XCD chunk.
  const int L = (blockIdx.x & 7) * 64 + (blockIdx.x >> 3);
  const int brow = (L & 3) * 256;          // batch tile
  const int t0   = (L >> 2) * 256;         // t tile

  // ---- staging constants (per thread) ----
  // issue e = wv*2+q covers rows e*16 .. e*16+15; lane -> row e*16 + lane/4,
  // linear unit = lane&3; swizzle key (row>>1)&3 = (lane>>3)&3.
  const int srow0 = wv*32 + (lane >> 2);            // q=0 row
  const int sunit = (lane & 3) ^ ((lane >> 3) & 3); // inverse-swizzled unit
  const u16* sA0 = h   + (size_t)(brow + srow0     )*1024 + sunit*8;
  const u16* sA1 = h   + (size_t)(brow + srow0 + 16)*1024 + sunit*8;
  const u16* sB0 = W2b + (size_t)(t0   + srow0     )*1024 + sunit*8;
  const u16* sB1 = W2b + (size_t)(t0   + srow0 + 16)*1024 + sunit*8;
  const u32 dst0 = (u32)wv*2048u;                   // LDS byte, + lane*16 by HW
  const u32 dst1 = dst0 + 1024u;

  // ---- ds_read offsets (bytes). key = (fr>>1)&3, unit = lg ^ key ----
  const int fr = lane & 15, lg = lane >> 4;
  const u32 uoff = (u32)((lg ^ ((fr >> 1) & 3)) * 16);
  u32 aoff[8], boff[4];
#pragma unroll
  for (int m = 0; m < 8; ++m)
    aoff[m] = (u32)((wr*128 + m*16 + fr) * 64) + uoff;
#pragma unroll
  for (int n = 0; n < 4; ++n)
    boff[n] = 16384u + (u32)((wc*64 + n*16 + fr) * 64) + uoff;

  char* ldsb = (char*)lds;
  f32x4 acc[8][4] = {};

  // ---- prologue: A(0), B(0), A(1); keep A(1)'s 2 loads outstanding ----
  gload_lds16(sA0,      ldsb + dst0);
  gload_lds16(sA1,      ldsb + dst1);
  gload_lds16(sB0,      ldsb + 16384u + dst0);
  gload_lds16(sB1,      ldsb + 16384u + dst1);
  gload_lds16(sA0 + 32, ldsb + 32768u + dst0);
  gload_lds16(sA1 + 32, ldsb + 32768u + dst1);
  asm volatile("s_waitcnt vmcnt(2)" ::: "memory");
  MEMFENCE; __builtin_amdgcn_s_barrier(); MEMFENCE;

#pragma unroll 2
  for (int t = 0; t < 32; ++t) {
    const u32 rbase = (u32)(t & 1) * 32768u;                 // read parity
    const int kbB = ((t+1 < 32) ? t+1 : 31) * 32;            // elems
    const int kbA = ((t+2 < 32) ? t+2 : 31) * 32;
    const u32 wbB = (u32)((t+1) & 1) * 32768u + 16384u;      // B(t+1) dest
    const u32 wbA = (u32)(t & 1) * 32768u;                   // A(t+2) dest

    // ================= phase j0: MFMA n=0,1 =================
    bf16x8 af[8], bf0, bf1;
#pragma unroll
    for (int m = 0; m < 8; ++m)
      af[m] = *(const bf16x8*)(ldsb + rbase + aoff[m]);
    bf0 = *(const bf16x8*)(ldsb + rbase + boff[0]);
    bf1 = *(const bf16x8*)(ldsb + rbase + boff[1]);
    gload_lds16(sB0 + kbB, ldsb + wbB + dst0);
    gload_lds16(sB1 + kbB, ldsb + wbB + dst1);
    MEMFENCE; __builtin_amdgcn_s_barrier();
    asm volatile("s_waitcnt lgkmcnt(0)" ::: "memory");
    __builtin_amdgcn_sched_barrier(0);
    __builtin_amdgcn_s_setprio(1);
#pragma unroll
    for (int m = 0; m < 8; ++m) {
      acc[m][0] = __builtin_amdgcn_mfma_f32_16x16x32_bf16(af[m], bf0, acc[m][0], 0,0,0);
      acc[m][1] = __builtin_amdgcn_mfma_f32_16x16x32_bf16(af[m], bf1, acc[m][1], 0,0,0);
    }
    __builtin_amdgcn_s_setprio(0);
    MEMFENCE; __builtin_amdgcn_s_barrier(); MEMFENCE;

    // ================= phase j1: MFMA n=2,3 =================
    bf0 = *(const bf16x8*)(ldsb + rbase + boff[2]);
    bf1 = *(const bf16x8*)(ldsb + rbase + boff[3]);
    gload_lds16(sA0 + kbA, ldsb + wbA + dst0);
    gload_lds16(sA1 + kbA, ldsb + wbA + dst1);
    MEMFENCE; __builtin_amdgcn_s_barrier();
    asm volatile("s_waitcnt lgkmcnt(0)" ::: "memory");
    __builtin_amdgcn_sched_barrier(0);
    __builtin_amdgcn_s_setprio(1);
#pragma unroll
    for (int m = 0; m < 8; ++m) {
      acc[m][2] = __builtin_amdgcn_mfma_f32_16x16x32_bf16(af[m], bf0, acc[m][2], 0,0,0);
      acc[m][3] = __builtin_amdgcn_mfma_f32_16x16x32_bf16(af[m], bf1, acc[m][3], 0,0,0);
    }
    __builtin_amdgcn_s_setprio(0);
    asm volatile("s_waitcnt vmcnt(2)" ::: "memory");   // B(t+1),A(t+1) landed
    MEMFENCE; __builtin_amdgcn_s_barrier(); MEMFENCE;
  }

  // ---- epilogue: t -> (i,j) strict-lower scatter, forward half only ----
#pragma unroll
  for (int n = 0; n < 4; ++n) {
    const int t = t0 + wc*64 + n*16 + fr;
    if (t >= TRI) continue;
    const float bias = b2[t];
    int i = (int)((1.0f + sqrtf((float)(8*t + 1))) * 0.5f);
    while (i*(i+1)/2 <= t) ++i;
    while (i*(i-1)/2 > t) --i;
    const int j = t - i*(i-1)/2;
    const int ijbase = i*256 + j;
#pragma unroll
    for (int m = 0; m < 8; ++m) {
      const int row0 = brow + wr*128 + m*16 + (lane >> 4)*4;
#pragma unroll
      for (int r = 0; r < 4; ++r)
        out[(size_t)(row0 + r)*65536 + ijbase] = acc[m][n][r] + bias;
    }
  }
}

// ---------------------------------------------------------------------------
// Fallback path (ws too small): round-1 kernels, proven correct.
// ---------------------------------------------------------------------------
__global__ __launch_bounds__(256)
void k1_gemm_softplus(const float* __restrict__ x, const float* __restrict__ W1,
                      const float* __restrict__ b1, u16* __restrict__ h)
{
  __shared__ float ldsA[128*32];
  __shared__ float ldsB[128*32];
  const int tid = threadIdx.x, lane = tid & 63, wave = tid >> 6;
  const int wm = wave >> 1, wn = wave & 1;
  const int brow = (blockIdx.x & 7) * 128, bcol = (blockIdx.x >> 3) * 128;
  const int s_row = wave*8 + (lane >> 3);
  const int s_col = (lane & 7) * 4;
  const float* gA = x  + (brow + s_row)*256 + s_col;
  const float* gB = W1 + (bcol + s_row)*256 + s_col;
  float* lA = &ldsA[wave*256];
  float* lB = &ldsB[wave*256];
  const int fr = lane & 15, fk = (lane >> 4) * 8;
  const float* rdA = &ldsA[(wm*64 + fr)*32 + fk];
  const float* rdB = &ldsB[(wn*64 + fr)*32 + fk];
  f32x4 acc[4][4] = {};
  for (int kt = 0; kt < 8; ++kt) {
    __syncthreads();
#pragma unroll
    for (int q = 0; q < 4; ++q) {
      gload_lds16(gA + q*32*256 + kt*32, lA + q*1024);
      gload_lds16(gB + q*32*256 + kt*32, lB + q*1024);
    }
    __syncthreads();
    bf16x8 af[4], bfv[4];
#pragma unroll
    for (int m = 0; m < 4; ++m) {
      f32x4 lo = *(const f32x4*)(rdA + m*512);
      f32x4 hi = *(const f32x4*)(rdA + m*512 + 4);
      u32x4 p = { pack2bf(lo.x,lo.y), pack2bf(lo.z,lo.w),
                  pack2bf(hi.x,hi.y), pack2bf(hi.z,hi.w) };
      af[m] = __builtin_bit_cast(bf16x8, p);
    }
#pragma unroll
    for (int n = 0; n < 4; ++n) {
      f32x4 lo = *(const f32x4*)(rdB + n*512);
      f32x4 hi = *(const f32x4*)(rdB + n*512 + 4);
      u32x4 p = { pack2bf(lo.x,lo.y), pack2bf(lo.z,lo.w),
                  pack2bf(hi.x,hi.y), pack2bf(hi.z,hi.w) };
      bfv[n] = __builtin_bit_cast(bf16x8, p);
    }
#pragma unroll
    for (int m = 0; m < 4; ++m)
#pragma unroll
      for (int n = 0; n < 4; ++n)
        acc[m][n] = __builtin_amdgcn_mfma_f32_16x16x32_bf16(af[m], bfv[n], acc[m][n], 0,0,0);
  }
#pragma unroll
  for (int n = 0; n < 4; ++n) {
    const int col = bcol + wn*64 + n*16 + fr;
    const float bias = b1[col];
#pragma unroll
    for (int m = 0; m < 4; ++m) {
      const int row0 = brow + wm*64 + m*16 + (lane >> 4)*4;
#pragma unroll
      for (int r = 0; r < 4; ++r) {
        float z = acc[m][n][r] + bias;
        float sp = fmaxf(z, 0.f) + log1pf(expf(-fabsf(z)));
        h[(row0 + r)*1024 + col] = f2bf_rn(sp);
      }
    }
  }
}

__global__ __launch_bounds__(256)
void k2_gemm_scatter(const u16* __restrict__ h, const float* __restrict__ W2,
                     const float* __restrict__ b2, float* __restrict__ out)
{
  __shared__ u16   ldsA[128*32];
  __shared__ float ldsB[128*32];
  const int tid = threadIdx.x, lane = tid & 63, wave = tid >> 6;
  const int wm = wave >> 1, wn = wave & 1;
  const int bid = blockIdx.x;
  const int L  = (bid & 7) * 255 + (bid >> 3);
  const int t0 = (L >> 3) * 128;
  const int brow = (L & 7) * 128;
  const int a_row = wave*16 + (lane >> 2);
  const int a_col = (lane & 3) * 8;
  const u16* gA = h + (brow + a_row)*1024 + a_col;
  u16* lA = &ldsA[wave*512];
  const int b_row = wave*8 + (lane >> 3);
  const int b_col = (lane & 7) * 4;
  const float* gB = W2 + (size_t)(t0 + b_row)*1024 + b_col;
  float* lB = &ldsB[wave*256];
  const int fr = lane & 15, fk = (lane >> 4) * 8;
  const u16*   rdA = &ldsA[(wm*64 + fr)*32 + fk];
  const float* rdB = &ldsB[(wn*64 + fr)*32 + fk];
  f32x4 acc[4][4] = {};
  for (int kt = 0; kt < 32; ++kt) {
    __syncthreads();
#pragma unroll
    for (int q = 0; q < 2; ++q)
      gload_lds16(gA + q*64*1024 + kt*32, lA + q*2048);
#pragma unroll
    for (int q = 0; q < 4; ++q)
      gload_lds16(gB + q*32*1024 + kt*32, lB + q*1024);
    __syncthreads();
    bf16x8 af[4];
#pragma unroll
    for (int m = 0; m < 4; ++m)
      af[m] = *(const bf16x8*)(rdA + m*512);
#pragma unroll
    for (int n = 0; n < 4; ++n) {
      f32x4 lo = *(const f32x4*)(rdB + n*512);
      f32x4 hi = *(const f32x4*)(rdB + n*512 + 4);
      u32x4 p = { pack2bf(lo.x,lo.y), pack2bf(lo.z,lo.w),
                  pack2bf(hi.x,hi.y), pack2bf(hi.z,hi.w) };
      bf16x8 bfr = __builtin_bit_cast(bf16x8, p);
#pragma unroll
      for (int m = 0; m < 4; ++m)
        acc[m][n] = __builtin_amdgcn_mfma_f32_16x16x32_bf16(af[m], bfr, acc[m][n], 0,0,0);
    }
  }
#pragma unroll
  for (int n = 0; n < 4; ++n) {
    const int t = t0 + wn*64 + n*16 + fr;
    const float bias = b2[t];
    int i = (int)((1.0f + sqrtf((float)(8*t + 1))) * 0.5f);
    while (i*(i+1)/2 <= t) ++i;
    while (i*(i-1)/2 > t) --i;
    const int j = t - i*(i-1)/2;
    const int ijbase = i*256 + j;
#pragma unroll
    for (int m = 0; m < 4; ++m) {
      const int row0 = brow + wm*64 + m*16 + (lane >> 4)*4;
#pragma unroll
      for (int r = 0; r < 4; ++r)
        out[(size_t)(row0 + r)*65536 + ijbase] = acc[m][n][r] + bias;
    }
  }
}

// ---------------------------------------------------------------------------
// K3: antisymmetrize. Read lower 64x64 tiles, write -tile^T to upper.
// ---------------------------------------------------------------------------
__global__ __launch_bounds__(256)
void k3_mirror(float* __restrict__ out)
{
  __shared__ float tile[64][65];
  const int b = blockIdx.y;
  const int k = blockIdx.x;
  int ib, jb;
  if (k < 4) { ib = k; jb = k; }
  else {
    const int pi[6] = {1,2,2,3,3,3};
    const int pj[6] = {0,0,1,0,1,2};
    ib = pi[k-4]; jb = pj[k-4];
  }
  const int i0 = ib*64, j0 = jb*64;
  float* A = out + (size_t)b*65536;
  const int tid = threadIdx.x;
  const int r = tid >> 2, c0 = (tid & 3) * 16;
#pragma unroll
  for (int q = 0; q < 4; ++q) {
    const float4 v = *(const float4*)(A + (i0 + r)*256 + j0 + c0 + q*4);
    tile[r][c0+q*4+0] = v.x;
    tile[r][c0+q*4+1] = v.y;
    tile[r][c0+q*4+2] = v.z;
    tile[r][c0+q*4+3] = v.w;
  }
  __syncthreads();
  if (ib != jb) {
#pragma unroll
    for (int q = 0; q < 4; ++q) {
      const int c = c0 + q*4;
      float4 v;
      v.x = -tile[c+0][r]; v.y = -tile[c+1][r];
      v.z = -tile[c+2][r]; v.w = -tile[c+3][r];
      *(float4*)(A + (j0 + r)*256 + i0 + c) = v;
    }
  } else {
#pragma unroll
    for (int q = 0; q < 4; ++q) {
      const int cb = c0 + q*4;
      float4 v;
#pragma unroll
      for (int e = 0; e < 4; ++e) {
        const int c = cb + e;
        float val = (c < r) ? tile[r][c] : ((c == r) ? 0.f : -tile[c][r]);
        ((float*)&v)[e] = val;
      }
      *(float4*)(A + (i0 + r)*256 + j0 + cb) = v;
    }
  }
}

// ---------------------------------------------------------------------------
extern "C" void kernel_launch(void* const* d_in, const int* in_sizes, int n_in,
                              void* d_out, int out_size, void* d_ws, size_t ws_size,
                              hipStream_t stream) {
  const float* x  = (const float*)d_in[0];
  const float* W1 = (const float*)d_in[1];
  const float* b1 = (const float*)d_in[2];
  const float* W2 = (const float*)d_in[3];
  const float* b2 = (const float*)d_in[4];
  float* out = (float*)d_out;
  u16* h = (u16*)d_ws;                               // 2 MB

  const size_t need = 2u*1024*1024 + (size_t)NPAD*1024*2;   // h + W2 bf16 (padded)
  if (ws_size >= need) {
    u16* W2b = (u16*)((char*)d_ws + 2u*1024*1024);
    k0_fused        <<<dim3(64 + 1024), dim3(256), 0, stream>>>(x, W1, b1, h, W2, W2b);
    k2_gemm_8phase  <<<dim3(512),       dim3(512), 0, stream>>>(h, W2b, b2, out);
  } else {
    k1_gemm_softplus<<<dim3(64),        dim3(256), 0, stream>>>(x, W1, b1, h);
    k2_gemm_scatter <<<dim3(2040),      dim3(256), 0, stream>>>(h, W2, b2, out);
  }
  k3_mirror         <<<dim3(10, 1024),  dim3(256), 0, stream>>>(out);
}